// Round 10
// baseline (238.857 us; speedup 1.0000x reference)
//
#include <hip/hip_runtime.h>
#include <math.h>

// ---------------------------------------------------------------------------
// 3-layer GCN + softmax on MI355X.
// A(XW) = (AX)W -> aggregate first (F=6 for layer 1).
// R9: occupancy fixes for the build pipeline (binscatter CHUNK 2048 -> 782
//     blocks; build 512 threads; wprep folded into build's extra blocks) and
//     8-deep independent load chains in the gather loops (agg64 / layer1).
//     Structure otherwise identical to R8 (232 us).
// ---------------------------------------------------------------------------

#define BLK 256
#define BLKB 512           // k_build threads
#define SKB 256            // scatter buckets: b = col >> 8 (196 active)
#define CHUNK 2048         // edges staged per block in k_binscatter

typedef __attribute__((ext_vector_type(8))) short bf16x8;
typedef __attribute__((ext_vector_type(4))) float f32x4;

__device__ inline unsigned short f2bf(float f) {      // fp32 -> bf16 (RNE)
  unsigned u = __float_as_uint(f);
  return (unsigned short)((u + 0x7FFF + ((u >> 16) & 1)) >> 16);
}
__device__ inline float bflo(unsigned u) { return __uint_as_float(u << 16); }
__device__ inline float bfhi(unsigned u) { return __uint_as_float(u & 0xFFFF0000u); }

// ---- pass A: LDS-binned scatter into fixed-capacity bucket regions ---------
// Entry: .x = row | (col << 16)  (N < 65536), .y = float bits of w.

__global__ __launch_bounds__(256) void k_binscatter(
    const int* __restrict__ row, const int* __restrict__ col,
    const float* __restrict__ w, int E,
    int* __restrict__ bfill, int2* __restrict__ bucket, int CAP) {
  __shared__ int2 stage[CHUNK];
  __shared__ int lhist[SKB], lbase[SKB], gbase[SKB], lfill[SKB];
  int t = threadIdx.x;
  int e0 = blockIdx.x * CHUNK;
  int n = E - e0; if (n > CHUNK) n = CHUNK;
  lhist[t] = 0; lfill[t] = 0;
  __syncthreads();
  for (int i = t; i < n; i += BLK) atomicAdd(&lhist[((unsigned)col[e0 + i]) >> 8], 1);
  __syncthreads();
  lbase[t] = lhist[t];
  __syncthreads();
  for (int off = 1; off < SKB; off <<= 1) {
    int v = (t >= off) ? lbase[t - off] : 0;
    __syncthreads();
    lbase[t] += v;
    __syncthreads();
  }
  int excl = lbase[t] - lhist[t];
  int cb = lhist[t];
  gbase[t] = cb ? atomicAdd(&bfill[t << 4], cb) : 0;   // reserve run space
  __syncthreads();
  lbase[t] = excl;
  __syncthreads();
  for (int i = t; i < n; i += BLK) {
    int c = col[e0 + i];
    int b = ((unsigned)c) >> 8;
    int r = atomicAdd(&lfill[b], 1);
    stage[lbase[b] + r] = make_int2(row[e0 + i] | (c << 16), __float_as_int(w[e0 + i]));
  }
  __syncthreads();
  for (int i = t; i < n; i += BLK) {
    int2 p = stage[i];
    int b = ((unsigned)p.x) >> 24;
    bucket[(size_t)b * CAP + gbase[b] + (i - lbase[b])] = p;
  }
}

// ---- pass B: workgroup per bucket -> node-ordered packed CSR + norms -------
// Extra blocks (b >= NBb) convert W2/W3 to bf16 (folds the old k_wprep).

__global__ __launch_bounds__(512) void k_build(
    const int2* __restrict__ bucket, const int* __restrict__ bfill,
    const float* __restrict__ x,
    unsigned* __restrict__ csr, int* __restrict__ cnt, int* __restrict__ start,
    float* __restrict__ dis, unsigned short* __restrict__ x8b, int CAP, int N,
    int NBb, const float* __restrict__ W2, const float* __restrict__ W3,
    unsigned short* __restrict__ W2b, unsigned short* __restrict__ W3b) {
  __shared__ int   hist[SKB];
  __shared__ float wsum[SKB];
  __shared__ int   lstart[SKB + 1];
  __shared__ int   lfill[SKB];
  int b = blockIdx.x, t = threadIdx.x;
  if (b >= NBb) {                              // wprep tail blocks
    int i = (b - NBb) * BLKB + t;
    if (i < 4096) { W2b[i] = f2bf(W2[i]); W3b[i] = f2bf(W3[i]); }
    return;
  }
  int n0 = b << 8;
  int M = N - n0; if (M > 256) M = 256;
  if (M <= 0) return;
  if (t < SKB) { hist[t] = 0; wsum[t] = 0.0f; lfill[t] = 0; }
  __syncthreads();
  const int2* bb = bucket + (size_t)b * CAP;
  int ec = bfill[b << 4];
  for (int i = t; i < ec; i += BLKB) {
    int2 p = bb[i];
    int lc = (((unsigned)p.x) >> 16) & 255;
    atomicAdd(&hist[lc], 1);
    atomicAdd(&wsum[lc], __int_as_float(p.y));          // exact fp32 degree
  }
  __syncthreads();
  if (t == 0) {
    int run = 0;
    for (int i = 0; i < M; ++i) { lstart[i] = run; run += hist[i]; }
    lstart[M] = run;
  }
  __syncthreads();
  if (t < M) {
    int n = n0 + t;
    cnt[n] = hist[t];
    start[n] = b * CAP + lstart[t];
    float d = 1.0f / sqrtf(wsum[t] + 1.0f);
    dis[n] = d;
    const float* xr = x + (size_t)n * 6;
    uint4 pk;
    pk.x = (unsigned)f2bf(d * xr[0]) | ((unsigned)f2bf(d * xr[1]) << 16);
    pk.y = (unsigned)f2bf(d * xr[2]) | ((unsigned)f2bf(d * xr[3]) << 16);
    pk.z = (unsigned)f2bf(d * xr[4]) | ((unsigned)f2bf(d * xr[5]) << 16);
    pk.w = 0u;
    *(uint4*)(x8b + (size_t)n * 8) = pk;
  }
  __syncthreads();
  for (int i = t; i < ec; i += BLKB) {
    int2 p = bb[i];
    int lc = (((unsigned)p.x) >> 16) & 255;
    int pos = lstart[lc] + atomicAdd(&lfill[lc], 1);
    csr[(size_t)b * CAP + pos] =
        ((unsigned)p.x & 0xFFFFu) | ((unsigned)f2bf(__int_as_float(p.y)) << 16);
  }
}

// ---- layer 1 fused: aggregate F=6 bf16 feats + dense 6->64 + sigmoid -------

__global__ void k_layer1(const unsigned short* __restrict__ x8b,
                         const int* __restrict__ start, const int* __restrict__ cnt,
                         const unsigned* __restrict__ csr, const float* __restrict__ dis,
                         const float* __restrict__ W1, const float* __restrict__ b1,
                         unsigned short* __restrict__ hb, int N) {
  int n = blockIdx.x * blockDim.x + threadIdx.x;
  if (n >= N) return;
  uint4 sv = *(const uint4*)(x8b + (size_t)n * 8);     // self term = x'[n]
  float a0 = bflo(sv.x), a1 = bfhi(sv.x), a2 = bflo(sv.y);
  float a3 = bfhi(sv.y), a4 = bflo(sv.z), a5 = bfhi(sv.z);
  int s = start[n], e = s + cnt[n];
  int i = s;
  for (; i + 8 <= e; i += 8) {                 // 8 independent chains in flight
    unsigned p0 = csr[i],     p1 = csr[i + 1], p2 = csr[i + 2], p3 = csr[i + 3];
    unsigned p4 = csr[i + 4], p5 = csr[i + 5], p6 = csr[i + 6], p7 = csr[i + 7];
    uint4 h0 = *(const uint4*)(x8b + (size_t)(p0 & 0xFFFFu) * 8);
    uint4 h1 = *(const uint4*)(x8b + (size_t)(p1 & 0xFFFFu) * 8);
    uint4 h2 = *(const uint4*)(x8b + (size_t)(p2 & 0xFFFFu) * 8);
    uint4 h3 = *(const uint4*)(x8b + (size_t)(p3 & 0xFFFFu) * 8);
    uint4 h4 = *(const uint4*)(x8b + (size_t)(p4 & 0xFFFFu) * 8);
    uint4 h5 = *(const uint4*)(x8b + (size_t)(p5 & 0xFFFFu) * 8);
    uint4 h6 = *(const uint4*)(x8b + (size_t)(p6 & 0xFFFFu) * 8);
    uint4 h7 = *(const uint4*)(x8b + (size_t)(p7 & 0xFFFFu) * 8);
    float v0 = bfhi(p0), v1 = bfhi(p1), v2 = bfhi(p2), v3 = bfhi(p3);
    float v4 = bfhi(p4), v5 = bfhi(p5), v6 = bfhi(p6), v7 = bfhi(p7);
    a0 += v0*bflo(h0.x) + v1*bflo(h1.x) + v2*bflo(h2.x) + v3*bflo(h3.x)
        + v4*bflo(h4.x) + v5*bflo(h5.x) + v6*bflo(h6.x) + v7*bflo(h7.x);
    a1 += v0*bfhi(h0.x) + v1*bfhi(h1.x) + v2*bfhi(h2.x) + v3*bfhi(h3.x)
        + v4*bfhi(h4.x) + v5*bfhi(h5.x) + v6*bfhi(h6.x) + v7*bfhi(h7.x);
    a2 += v0*bflo(h0.y) + v1*bflo(h1.y) + v2*bflo(h2.y) + v3*bflo(h3.y)
        + v4*bflo(h4.y) + v5*bflo(h5.y) + v6*bflo(h6.y) + v7*bflo(h7.y);
    a3 += v0*bfhi(h0.y) + v1*bfhi(h1.y) + v2*bfhi(h2.y) + v3*bfhi(h3.y)
        + v4*bfhi(h4.y) + v5*bfhi(h5.y) + v6*bfhi(h6.y) + v7*bfhi(h7.y);
    a4 += v0*bflo(h0.z) + v1*bflo(h1.z) + v2*bflo(h2.z) + v3*bflo(h3.z)
        + v4*bflo(h4.z) + v5*bflo(h5.z) + v6*bflo(h6.z) + v7*bflo(h7.z);
    a5 += v0*bfhi(h0.z) + v1*bfhi(h1.z) + v2*bfhi(h2.z) + v3*bfhi(h3.z)
        + v4*bfhi(h4.z) + v5*bfhi(h5.z) + v6*bfhi(h6.z) + v7*bfhi(h7.z);
  }
  for (; i < e; ++i) {
    unsigned pe = csr[i];
    float v = bfhi(pe);
    uint4 hv = *(const uint4*)(x8b + (size_t)(pe & 0xFFFFu) * 8);
    a0 += v * bflo(hv.x); a1 += v * bfhi(hv.x);
    a2 += v * bflo(hv.y); a3 += v * bfhi(hv.y);
    a4 += v * bflo(hv.z); a5 += v * bfhi(hv.z);
  }
  float d = dis[n];
  a0 *= d; a1 *= d; a2 *= d; a3 *= d; a4 *= d; a5 *= d;
  unsigned short* o = hb + (size_t)n * 64;
#pragma unroll
  for (int j4 = 0; j4 < 16; ++j4) {
    float4 acc = *(const float4*)(b1 + j4 * 4);
    const float* Wc = W1 + j4 * 4;
    acc.x += a0*Wc[0] + a1*Wc[64] + a2*Wc[128] + a3*Wc[192] + a4*Wc[256] + a5*Wc[320];
    acc.y += a0*Wc[1] + a1*Wc[65] + a2*Wc[129] + a3*Wc[193] + a4*Wc[257] + a5*Wc[321];
    acc.z += a0*Wc[2] + a1*Wc[66] + a2*Wc[130] + a3*Wc[194] + a4*Wc[258] + a5*Wc[322];
    acc.w += a0*Wc[3] + a1*Wc[67] + a2*Wc[131] + a3*Wc[195] + a4*Wc[259] + a5*Wc[323];
    uint2 pk;
    pk.x = (unsigned)f2bf(d / (1.0f + expf(-acc.x))) |
           ((unsigned)f2bf(d / (1.0f + expf(-acc.y))) << 16);
    pk.y = (unsigned)f2bf(d / (1.0f + expf(-acc.z))) |
           ((unsigned)f2bf(d / (1.0f + expf(-acc.w))) << 16);
    *(uint2*)(o + j4 * 4) = pk;
  }
}

// ---- layers 2/3 aggregation: 8 lanes/node, 8x-unrolled gather, bf16 out ----

__global__ void k_agg64(const unsigned short* __restrict__ hb,
                        const int* __restrict__ start, const int* __restrict__ cnt,
                        const unsigned* __restrict__ csr, const float* __restrict__ dis,
                        unsigned short* __restrict__ aggb, int N) {
  int t = blockIdx.x * blockDim.x + threadIdx.x;
  int n = t >> 3, sub = t & 7;
  if (n >= N) return;
  uint4 sv = *(const uint4*)(hb + (size_t)n * 64 + sub * 8);   // self = h'[n]
  float a0 = bflo(sv.x), a1 = bfhi(sv.x), a2 = bflo(sv.y), a3 = bfhi(sv.y);
  float a4 = bflo(sv.z), a5 = bfhi(sv.z), a6 = bflo(sv.w), a7 = bfhi(sv.w);
  int s = start[n], e = s + cnt[n];
  int i = s;
  for (; i + 8 <= e; i += 8) {                 // 8 independent chains in flight
    unsigned p0 = csr[i],     p1 = csr[i + 1], p2 = csr[i + 2], p3 = csr[i + 3];
    unsigned p4 = csr[i + 4], p5 = csr[i + 5], p6 = csr[i + 6], p7 = csr[i + 7];
    uint4 h0 = *(const uint4*)(hb + (size_t)(p0 & 0xFFFFu) * 64 + sub * 8);
    uint4 h1 = *(const uint4*)(hb + (size_t)(p1 & 0xFFFFu) * 64 + sub * 8);
    uint4 h2 = *(const uint4*)(hb + (size_t)(p2 & 0xFFFFu) * 64 + sub * 8);
    uint4 h3 = *(const uint4*)(hb + (size_t)(p3 & 0xFFFFu) * 64 + sub * 8);
    uint4 h4 = *(const uint4*)(hb + (size_t)(p4 & 0xFFFFu) * 64 + sub * 8);
    uint4 h5 = *(const uint4*)(hb + (size_t)(p5 & 0xFFFFu) * 64 + sub * 8);
    uint4 h6 = *(const uint4*)(hb + (size_t)(p6 & 0xFFFFu) * 64 + sub * 8);
    uint4 h7 = *(const uint4*)(hb + (size_t)(p7 & 0xFFFFu) * 64 + sub * 8);
    float v0 = bfhi(p0), v1 = bfhi(p1), v2 = bfhi(p2), v3 = bfhi(p3);
    float v4 = bfhi(p4), v5 = bfhi(p5), v6 = bfhi(p6), v7 = bfhi(p7);
    a0 += v0*bflo(h0.x) + v1*bflo(h1.x) + v2*bflo(h2.x) + v3*bflo(h3.x)
        + v4*bflo(h4.x) + v5*bflo(h5.x) + v6*bflo(h6.x) + v7*bflo(h7.x);
    a1 += v0*bfhi(h0.x) + v1*bfhi(h1.x) + v2*bfhi(h2.x) + v3*bfhi(h3.x)
        + v4*bfhi(h4.x) + v5*bfhi(h5.x) + v6*bfhi(h6.x) + v7*bfhi(h7.x);
    a2 += v0*bflo(h0.y) + v1*bflo(h1.y) + v2*bflo(h2.y) + v3*bflo(h3.y)
        + v4*bflo(h4.y) + v5*bflo(h5.y) + v6*bflo(h6.y) + v7*bflo(h7.y);
    a3 += v0*bfhi(h0.y) + v1*bfhi(h1.y) + v2*bfhi(h2.y) + v3*bfhi(h3.y)
        + v4*bfhi(h4.y) + v5*bfhi(h5.y) + v6*bfhi(h6.y) + v7*bfhi(h7.y);
    a4 += v0*bflo(h0.z) + v1*bflo(h1.z) + v2*bflo(h2.z) + v3*bflo(h3.z)
        + v4*bflo(h4.z) + v5*bflo(h5.z) + v6*bflo(h6.z) + v7*bflo(h7.z);
    a5 += v0*bfhi(h0.z) + v1*bfhi(h1.z) + v2*bfhi(h2.z) + v3*bfhi(h3.z)
        + v4*bfhi(h4.z) + v5*bfhi(h5.z) + v6*bfhi(h6.z) + v7*bfhi(h7.z);
    a6 += v0*bflo(h0.w) + v1*bflo(h1.w) + v2*bflo(h2.w) + v3*bflo(h3.w)
        + v4*bflo(h4.w) + v5*bflo(h5.w) + v6*bflo(h6.w) + v7*bflo(h7.w);
    a7 += v0*bfhi(h0.w) + v1*bfhi(h1.w) + v2*bfhi(h2.w) + v3*bfhi(h3.w)
        + v4*bfhi(h4.w) + v5*bfhi(h5.w) + v6*bfhi(h6.w) + v7*bfhi(h7.w);
  }
  for (; i < e; ++i) {
    unsigned pe = csr[i];
    float v = bfhi(pe);
    uint4 hv = *(const uint4*)(hb + (size_t)(pe & 0xFFFFu) * 64 + sub * 8);
    a0 += v * bflo(hv.x); a1 += v * bfhi(hv.x);
    a2 += v * bflo(hv.y); a3 += v * bfhi(hv.y);
    a4 += v * bflo(hv.z); a5 += v * bfhi(hv.z);
    a6 += v * bflo(hv.w); a7 += v * bfhi(hv.w);
  }
  float d = dis[n];
  uint4 pk;
  pk.x = (unsigned)f2bf(d * a0) | ((unsigned)f2bf(d * a1) << 16);
  pk.y = (unsigned)f2bf(d * a2) | ((unsigned)f2bf(d * a3) << 16);
  pk.z = (unsigned)f2bf(d * a4) | ((unsigned)f2bf(d * a5) << 16);
  pk.w = (unsigned)f2bf(d * a6) | ((unsigned)f2bf(d * a7) << 16);
  *(uint4*)(aggb + (size_t)n * 64 + sub * 8) = pk;
}

// ---- MFMA dense 64->64 + bias + sigmoid + *dis -> bf16 h' ------------------

__global__ __launch_bounds__(256) void k_dense64_mfma(
    const unsigned short* __restrict__ aggb, const unsigned short* __restrict__ Wb,
    const float* __restrict__ b, const float* __restrict__ dis,
    unsigned short* __restrict__ hb, int NS) {
  int wid = threadIdx.x >> 6, lane = threadIdx.x & 63;
  int quad = lane >> 4, r16 = lane & 15;
  bf16x8 Bf[2][4];
#pragma unroll
  for (int kt = 0; kt < 2; ++kt)
#pragma unroll
    for (int jt = 0; jt < 4; ++jt)
#pragma unroll
      for (int j = 0; j < 8; ++j)
        Bf[kt][jt][j] = (short)Wb[(kt * 32 + quad * 8 + j) * 64 + jt * 16 + r16];
  float bias[4];
#pragma unroll
  for (int jt = 0; jt < 4; ++jt) bias[jt] = b[jt * 16 + r16];
  int stride = gridDim.x * 4;
  for (int s = blockIdx.x * 4 + wid; s < NS; s += stride) {
    int n0 = s * 16;
    bf16x8 Af0 = *(const bf16x8*)(aggb + (size_t)(n0 + r16) * 64 + quad * 8);
    bf16x8 Af1 = *(const bf16x8*)(aggb + (size_t)(n0 + r16) * 64 + 32 + quad * 8);
    f32x4 C[4];
#pragma unroll
    for (int jt = 0; jt < 4; ++jt) {
      f32x4 z = {0.f, 0.f, 0.f, 0.f};
      z = __builtin_amdgcn_mfma_f32_16x16x32_bf16(Af0, Bf[0][jt], z, 0, 0, 0);
      z = __builtin_amdgcn_mfma_f32_16x16x32_bf16(Af1, Bf[1][jt], z, 0, 0, 0);
      C[jt] = z;
    }
    float dv[4];
#pragma unroll
    for (int reg = 0; reg < 4; ++reg) dv[reg] = dis[n0 + quad * 4 + reg];
#pragma unroll
    for (int jt = 0; jt < 4; ++jt)
#pragma unroll
      for (int reg = 0; reg < 4; ++reg) {
        float h = dv[reg] / (1.0f + expf(-(C[jt][reg] + bias[jt])));
        hb[(size_t)(n0 + quad * 4 + reg) * 64 + jt * 16 + r16] = f2bf(h);
      }
  }
}

// ---- MFMA layer-3 dense + sigmoid + logit + exp + partial sum --------------

__global__ __launch_bounds__(256) void k_head_mfma(
    const unsigned short* __restrict__ aggb, const unsigned short* __restrict__ Wb,
    const float* __restrict__ b, const float* __restrict__ Wl,
    const float* __restrict__ bl, float* __restrict__ expv,
    float* __restrict__ red_part, int NS) {
  int wid = threadIdx.x >> 6, lane = threadIdx.x & 63;
  int quad = lane >> 4, r16 = lane & 15;
  bf16x8 Bf[2][4];
#pragma unroll
  for (int kt = 0; kt < 2; ++kt)
#pragma unroll
    for (int jt = 0; jt < 4; ++jt)
#pragma unroll
      for (int j = 0; j < 8; ++j)
        Bf[kt][jt][j] = (short)Wb[(kt * 32 + quad * 8 + j) * 64 + jt * 16 + r16];
  float bias[4], wlv[4];
#pragma unroll
  for (int jt = 0; jt < 4; ++jt) {
    bias[jt] = b[jt * 16 + r16];
    wlv[jt]  = Wl[jt * 16 + r16];
  }
  float bl0 = bl[0];
  float lsum = 0.0f;
  int stride = gridDim.x * 4;
  for (int s = blockIdx.x * 4 + wid; s < NS; s += stride) {
    int n0 = s * 16;
    bf16x8 Af0 = *(const bf16x8*)(aggb + (size_t)(n0 + r16) * 64 + quad * 8);
    bf16x8 Af1 = *(const bf16x8*)(aggb + (size_t)(n0 + r16) * 64 + 32 + quad * 8);
    f32x4 C[4];
#pragma unroll
    for (int jt = 0; jt < 4; ++jt) {
      f32x4 z = {0.f, 0.f, 0.f, 0.f};
      z = __builtin_amdgcn_mfma_f32_16x16x32_bf16(Af0, Bf[0][jt], z, 0, 0, 0);
      z = __builtin_amdgcn_mfma_f32_16x16x32_bf16(Af1, Bf[1][jt], z, 0, 0, 0);
      C[jt] = z;
    }
    float p0 = 0, p1 = 0, p2 = 0, p3 = 0;
#pragma unroll
    for (int jt = 0; jt < 4; ++jt) {
      p0 += wlv[jt] / (1.0f + expf(-(C[jt][0] + bias[jt])));
      p1 += wlv[jt] / (1.0f + expf(-(C[jt][1] + bias[jt])));
      p2 += wlv[jt] / (1.0f + expf(-(C[jt][2] + bias[jt])));
      p3 += wlv[jt] / (1.0f + expf(-(C[jt][3] + bias[jt])));
    }
#pragma unroll
    for (int m = 1; m < 16; m <<= 1) {        // reduce over the 16 cols/quad
      p0 += __shfl_xor(p0, m, 64);
      p1 += __shfl_xor(p1, m, 64);
      p2 += __shfl_xor(p2, m, 64);
      p3 += __shfl_xor(p3, m, 64);
    }
    float ls = 0.0f;
    if (r16 == 0) {
      float e0 = expf(p0 + bl0), e1 = expf(p1 + bl0);
      float e2 = expf(p2 + bl0), e3 = expf(p3 + bl0);
      int r = n0 + quad * 4;
      expv[r] = e0; expv[r + 1] = e1; expv[r + 2] = e2; expv[r + 3] = e3;
      ls = e0 + e1 + e2 + e3;
    }
    ls += __shfl_xor(ls, 16, 64);
    ls += __shfl_xor(ls, 32, 64);
    lsum += ls;                                // lane 0 holds wave total
  }
  if (lane == 0) atomicAdd(&red_part[(blockIdx.x & 63) << 4], lsum);
}

// scale by 1/sum (each wave reduces the 64 padded partials; L2-hot)
__global__ void k_out(const float* __restrict__ expv, int N,
                      const float* __restrict__ red_part, float* __restrict__ out) {
  int i = blockIdx.x * blockDim.x + threadIdx.x;
  int lane = threadIdx.x & 63;
  float s = red_part[lane << 4];
#pragma unroll
  for (int o = 32; o > 0; o >>= 1) s += __shfl_down(s, o, 64);
  s = __shfl(s, 0, 64);
  if (i < N) out[i] = expv[i] / s;
}

// ---------------------------------------------------------------------------

extern "C" void kernel_launch(void* const* d_in, const int* in_sizes, int n_in,
                              void* d_out, int out_size, void* d_ws, size_t ws_size,
                              hipStream_t stream) {
  const float* x   = (const float*)d_in[0];   // [N,6]
  const int*   edg = (const int*)d_in[1];     // [2,E] int32
  const float* w   = (const float*)d_in[2];   // [E]
  const float* W1  = (const float*)d_in[3];   // [6,64]
  const float* b1  = (const float*)d_in[4];
  const float* W2  = (const float*)d_in[5];   // [64,64]
  const float* b2  = (const float*)d_in[6];
  const float* W3  = (const float*)d_in[7];
  const float* b3  = (const float*)d_in[8];
  const float* Wl  = (const float*)d_in[9];   // [64,1]
  const float* bl  = (const float*)d_in[10];
  float* out = (float*)d_out;

  const int N = in_sizes[0] / 6;
  const int E = in_sizes[2];
  const int* row = edg;
  const int* col = edg + E;
  const int NB = (N + 255) >> 8;              // active buckets (196)
  const int NS = (N + 15) / 16;               // MFMA strips (3125)

  // ---- workspace layout ----
  size_t off = 0;
  char* base = (char*)d_ws;
  auto alloc = [&](size_t bytes) -> void* {
    void* p = base + off;
    off += (bytes + 255) & ~(size_t)255;
    return p;
  };
  int*   bfill    = (int*)alloc((size_t)SKB * 16 * 4);   // padded counters (zeroed)
  float* red_part = (float*)alloc((size_t)64 * 16 * 4);  // padded partials (zeroed)
  size_t zero_bytes = off;
  int*   cnt    = (int*)alloc((size_t)N * 4);
  int*   start  = (int*)alloc((size_t)N * 4);
  float* dis    = (float*)alloc((size_t)N * 4);
  float* expv   = (float*)alloc((size_t)N * 4);
  unsigned short* x8b = (unsigned short*)alloc((size_t)N * 8 * 2);   // bf16 x'
  unsigned short* hb  = (unsigned short*)alloc((size_t)N * 64 * 2);  // bf16 h'
  unsigned short* W2b = (unsigned short*)alloc(4096 * 2);
  unsigned short* W3b = (unsigned short*)alloc(4096 * 2);
  size_t remain = (ws_size > off) ? (ws_size - off) : 0;
  long long capn = ((long long)remain) / ((long long)NB * 12);
  int CAP = (int)capn;
  if (CAP > 9216) CAP = 9216;
  if (CAP < 8704) CAP = 8704;                 // mean 8163 + ~6 sigma floor
  unsigned* csr = (unsigned*)alloc((size_t)NB * CAP * 4);
  size_t aggsz = (size_t)N * 64 * 2;
  size_t bksz  = (size_t)NB * CAP * 8;
  void* shared_blk = alloc(aggsz > bksz ? aggsz : bksz);
  int2*           bucket = (int2*)shared_blk;           // dead after k_build
  unsigned short* aggb   = (unsigned short*)shared_blk; // bf16 agg buffer

  const int gE  = (E + CHUNK - 1) / CHUNK;    // 782 blocks
  const int gN  = (N + BLK - 1) / BLK;
  const int gN8 = (N * 8 + BLK - 1) / BLK;    // 8 threads per node
  const int gM  = 200;                        // MFMA dense grid (800 waves)
  const int gB  = NB + 8;                     // build + wprep tail blocks

  hipMemsetAsync(d_ws, 0, zero_bytes, stream);

  // CSR build (wprep folded into build's tail blocks)
  k_binscatter<<<gE, BLK, 0, stream>>>(row, col, w, E, bfill, bucket, CAP);
  k_build     <<<gB, BLKB, 0, stream>>>(bucket, bfill, x, csr, cnt, start, dis,
                                        x8b, CAP, N, NB, W2, W3, W2b, W3b);

  // layer 1 (fused agg + dense + sigmoid) -> hb (bf16)
  k_layer1<<<gN, BLK, 0, stream>>>(x8b, start, cnt, csr, dis, W1, b1, hb, N);

  // layer 2: agg (bf16 gather -> bf16 agg) ; MFMA dense -> hb (bf16)
  k_agg64       <<<gN8, BLK, 0, stream>>>(hb, start, cnt, csr, dis, aggb, N);
  k_dense64_mfma<<<gM,  BLK, 0, stream>>>(aggb, W2b, b2, dis, hb, NS);

  // layer 3: agg ; MFMA dense fused with logits head + exp + partial sums
  k_agg64    <<<gN8, BLK, 0, stream>>>(hb, start, cnt, csr, dis, aggb, N);
  k_head_mfma<<<gM,  BLK, 0, stream>>>(aggb, W3b, b3, Wl, bl, expv, red_part, NS);

  // normalize
  k_out<<<gN, BLK, 0, stream>>>(expv, N, red_part, out);
}

// Round 11
// 234.705 us; speedup vs baseline: 1.0177x; 1.0177x over previous
//
#include <hip/hip_runtime.h>
#include <math.h>

// ---------------------------------------------------------------------------
// 3-layer GCN + softmax on MI355X.
// A(XW) = (AX)W -> aggregate first (F=6 for layer 1).
// R10: base = R8 (232 us). Wave-count fixes for the latency-bound gathers:
//      layer1 8 lanes/node (781 -> 6250 waves; edge list striped across
//      lanes, shfl-xor reduce, dense split across lanes); agg64 16 lanes/node
//      uint2 loads 8-deep (6252 -> 12500 waves, full CU coverage).
//      R9's CHUNK/build changes reverted (neutral-negative).
// ---------------------------------------------------------------------------

#define BLK 256
#define SKB 256            // scatter buckets: b = col >> 8 (196 active)
#define CHUNK 4096         // edges staged per block in k_binscatter

typedef __attribute__((ext_vector_type(8))) short bf16x8;
typedef __attribute__((ext_vector_type(4))) float f32x4;

__device__ inline unsigned short f2bf(float f) {      // fp32 -> bf16 (RNE)
  unsigned u = __float_as_uint(f);
  return (unsigned short)((u + 0x7FFF + ((u >> 16) & 1)) >> 16);
}
__device__ inline float bflo(unsigned u) { return __uint_as_float(u << 16); }
__device__ inline float bfhi(unsigned u) { return __uint_as_float(u & 0xFFFF0000u); }

// ---- pass A: LDS-binned scatter into fixed-capacity bucket regions ---------
// Entry: .x = row | (col << 16)  (N < 65536), .y = float bits of w.

__global__ __launch_bounds__(256) void k_binscatter(
    const int* __restrict__ row, const int* __restrict__ col,
    const float* __restrict__ w, int E,
    int* __restrict__ bfill, int2* __restrict__ bucket, int CAP) {
  __shared__ int2 stage[CHUNK];
  __shared__ int lhist[SKB], lbase[SKB], gbase[SKB], lfill[SKB];
  int t = threadIdx.x;
  int e0 = blockIdx.x * CHUNK;
  int n = E - e0; if (n > CHUNK) n = CHUNK;
  lhist[t] = 0; lfill[t] = 0;
  __syncthreads();
  for (int i = t; i < n; i += BLK) atomicAdd(&lhist[((unsigned)col[e0 + i]) >> 8], 1);
  __syncthreads();
  lbase[t] = lhist[t];
  __syncthreads();
  for (int off = 1; off < SKB; off <<= 1) {
    int v = (t >= off) ? lbase[t - off] : 0;
    __syncthreads();
    lbase[t] += v;
    __syncthreads();
  }
  int excl = lbase[t] - lhist[t];
  int cb = lhist[t];
  gbase[t] = cb ? atomicAdd(&bfill[t << 4], cb) : 0;   // reserve run space
  __syncthreads();
  lbase[t] = excl;
  __syncthreads();
  for (int i = t; i < n; i += BLK) {
    int c = col[e0 + i];
    int b = ((unsigned)c) >> 8;
    int r = atomicAdd(&lfill[b], 1);
    stage[lbase[b] + r] = make_int2(row[e0 + i] | (c << 16), __float_as_int(w[e0 + i]));
  }
  __syncthreads();
  for (int i = t; i < n; i += BLK) {
    int2 p = stage[i];
    int b = ((unsigned)p.x) >> 24;
    bucket[(size_t)b * CAP + gbase[b] + (i - lbase[b])] = p;
  }
}

// ---- pass B: workgroup per bucket -> node-ordered packed CSR + norms -------

__global__ __launch_bounds__(256) void k_build(
    const int2* __restrict__ bucket, const int* __restrict__ bfill,
    const float* __restrict__ x,
    unsigned* __restrict__ csr, int* __restrict__ cnt, int* __restrict__ start,
    float* __restrict__ dis, unsigned short* __restrict__ x8b, int CAP, int N) {
  __shared__ int   hist[SKB];
  __shared__ float wsum[SKB];
  __shared__ int   lstart[SKB + 1];
  __shared__ int   lfill[SKB];
  int b = blockIdx.x, t = threadIdx.x;
  int n0 = b << 8;
  int M = N - n0; if (M > 256) M = 256;
  if (M <= 0) return;
  hist[t] = 0; wsum[t] = 0.0f; lfill[t] = 0;
  __syncthreads();
  const int2* bb = bucket + (size_t)b * CAP;
  int ec = bfill[b << 4];
  for (int i = t; i < ec; i += BLK) {
    int2 p = bb[i];
    int lc = (((unsigned)p.x) >> 16) & 255;
    atomicAdd(&hist[lc], 1);
    atomicAdd(&wsum[lc], __int_as_float(p.y));          // exact fp32 degree
  }
  __syncthreads();
  if (t == 0) {
    int run = 0;
    for (int i = 0; i < M; ++i) { lstart[i] = run; run += hist[i]; }
    lstart[M] = run;
  }
  __syncthreads();
  if (t < M) {
    int n = n0 + t;
    cnt[n] = hist[t];
    start[n] = b * CAP + lstart[t];
    float d = 1.0f / sqrtf(wsum[t] + 1.0f);
    dis[n] = d;
    const float* xr = x + (size_t)n * 6;
    uint4 pk;
    pk.x = (unsigned)f2bf(d * xr[0]) | ((unsigned)f2bf(d * xr[1]) << 16);
    pk.y = (unsigned)f2bf(d * xr[2]) | ((unsigned)f2bf(d * xr[3]) << 16);
    pk.z = (unsigned)f2bf(d * xr[4]) | ((unsigned)f2bf(d * xr[5]) << 16);
    pk.w = 0u;
    *(uint4*)(x8b + (size_t)n * 8) = pk;
  }
  __syncthreads();
  for (int i = t; i < ec; i += BLK) {
    int2 p = bb[i];
    int lc = (((unsigned)p.x) >> 16) & 255;
    int pos = lstart[lc] + atomicAdd(&lfill[lc], 1);
    csr[(size_t)b * CAP + pos] =
        ((unsigned)p.x & 0xFFFFu) | ((unsigned)f2bf(__int_as_float(p.y)) << 16);
  }
}

// ---- W fp32 -> bf16 prep ---------------------------------------------------

__global__ void k_wprep(const float* __restrict__ W2, const float* __restrict__ W3,
                        unsigned short* __restrict__ W2b, unsigned short* __restrict__ W3b) {
  int i = blockIdx.x * blockDim.x + threadIdx.x;
  if (i < 4096) { W2b[i] = f2bf(W2[i]); W3b[i] = f2bf(W3[i]); }
}

// ---- layer 1: 8 lanes/node. Lanes stripe the edge list (coalesced csr),
// 2-deep unroll, shfl-xor reduce over the 8 lanes, dense split across lanes.

__global__ void k_layer1(const unsigned short* __restrict__ x8b,
                         const int* __restrict__ start, const int* __restrict__ cnt,
                         const unsigned* __restrict__ csr, const float* __restrict__ dis,
                         const float* __restrict__ W1, const float* __restrict__ b1,
                         unsigned short* __restrict__ hb, int N) {
  int t = blockIdx.x * blockDim.x + threadIdx.x;
  int n = t >> 3, sub = t & 7;
  if (n >= N) return;
  float a0 = 0.f, a1 = 0.f, a2 = 0.f, a3 = 0.f, a4 = 0.f, a5 = 0.f;
  if (sub == 0) {                              // self term = x'[n] on lane 0
    uint4 sv = *(const uint4*)(x8b + (size_t)n * 8);
    a0 = bflo(sv.x); a1 = bfhi(sv.x); a2 = bflo(sv.y);
    a3 = bfhi(sv.y); a4 = bflo(sv.z); a5 = bfhi(sv.z);
  }
  int s = start[n], e = s + cnt[n];
  int i = s + sub;
  for (; i + 8 < e; i += 16) {                 // 2 rows in flight per lane
    unsigned p0 = csr[i], p1 = csr[i + 8];
    uint4 h0 = *(const uint4*)(x8b + (size_t)(p0 & 0xFFFFu) * 8);
    uint4 h1 = *(const uint4*)(x8b + (size_t)(p1 & 0xFFFFu) * 8);
    float v0 = bfhi(p0), v1 = bfhi(p1);
    a0 += v0 * bflo(h0.x) + v1 * bflo(h1.x);
    a1 += v0 * bfhi(h0.x) + v1 * bfhi(h1.x);
    a2 += v0 * bflo(h0.y) + v1 * bflo(h1.y);
    a3 += v0 * bfhi(h0.y) + v1 * bfhi(h1.y);
    a4 += v0 * bflo(h0.z) + v1 * bflo(h1.z);
    a5 += v0 * bfhi(h0.z) + v1 * bfhi(h1.z);
  }
  for (; i < e; i += 8) {
    unsigned pe = csr[i];
    float v = bfhi(pe);
    uint4 hv = *(const uint4*)(x8b + (size_t)(pe & 0xFFFFu) * 8);
    a0 += v * bflo(hv.x); a1 += v * bfhi(hv.x);
    a2 += v * bflo(hv.y); a3 += v * bfhi(hv.y);
    a4 += v * bflo(hv.z); a5 += v * bfhi(hv.z);
  }
#pragma unroll
  for (int m = 1; m < 8; m <<= 1) {            // all 8 lanes end with full sums
    a0 += __shfl_xor(a0, m, 64); a1 += __shfl_xor(a1, m, 64);
    a2 += __shfl_xor(a2, m, 64); a3 += __shfl_xor(a3, m, 64);
    a4 += __shfl_xor(a4, m, 64); a5 += __shfl_xor(a5, m, 64);
  }
  float d = dis[n];
  a0 *= d; a1 *= d; a2 *= d; a3 *= d; a4 *= d; a5 *= d;
  unsigned short* o = hb + (size_t)n * 64;
#pragma unroll
  for (int jj = 0; jj < 2; ++jj) {             // each lane: 8 of 64 outputs
    int j4 = sub * 2 + jj;
    float4 acc = *(const float4*)(b1 + j4 * 4);
    const float* Wc = W1 + j4 * 4;
    acc.x += a0*Wc[0] + a1*Wc[64] + a2*Wc[128] + a3*Wc[192] + a4*Wc[256] + a5*Wc[320];
    acc.y += a0*Wc[1] + a1*Wc[65] + a2*Wc[129] + a3*Wc[193] + a4*Wc[257] + a5*Wc[321];
    acc.z += a0*Wc[2] + a1*Wc[66] + a2*Wc[130] + a3*Wc[194] + a4*Wc[258] + a5*Wc[322];
    acc.w += a0*Wc[3] + a1*Wc[67] + a2*Wc[131] + a3*Wc[195] + a4*Wc[259] + a5*Wc[323];
    uint2 pk;
    pk.x = (unsigned)f2bf(d / (1.0f + expf(-acc.x))) |
           ((unsigned)f2bf(d / (1.0f + expf(-acc.y))) << 16);
    pk.y = (unsigned)f2bf(d / (1.0f + expf(-acc.z))) |
           ((unsigned)f2bf(d / (1.0f + expf(-acc.w))) << 16);
    *(uint2*)(o + j4 * 4) = pk;
  }
}

// ---- layers 2/3 aggregation: 16 lanes/node, uint2 loads, 8-deep unroll -----

__global__ void k_agg64(const unsigned short* __restrict__ hb,
                        const int* __restrict__ start, const int* __restrict__ cnt,
                        const unsigned* __restrict__ csr, const float* __restrict__ dis,
                        unsigned short* __restrict__ aggb, int N) {
  int t = blockIdx.x * blockDim.x + threadIdx.x;
  int n = t >> 4, sub = t & 15;
  if (n >= N) return;
  uint2 sv = *(const uint2*)(hb + (size_t)n * 64 + sub * 4);   // self = h'[n]
  float a0 = bflo(sv.x), a1 = bfhi(sv.x), a2 = bflo(sv.y), a3 = bfhi(sv.y);
  int s = start[n], e = s + cnt[n];
  int i = s;
  for (; i + 8 <= e; i += 8) {                 // 8 independent chains in flight
    unsigned p0 = csr[i],     p1 = csr[i + 1], p2 = csr[i + 2], p3 = csr[i + 3];
    unsigned p4 = csr[i + 4], p5 = csr[i + 5], p6 = csr[i + 6], p7 = csr[i + 7];
    uint2 h0 = *(const uint2*)(hb + (size_t)(p0 & 0xFFFFu) * 64 + sub * 4);
    uint2 h1 = *(const uint2*)(hb + (size_t)(p1 & 0xFFFFu) * 64 + sub * 4);
    uint2 h2 = *(const uint2*)(hb + (size_t)(p2 & 0xFFFFu) * 64 + sub * 4);
    uint2 h3 = *(const uint2*)(hb + (size_t)(p3 & 0xFFFFu) * 64 + sub * 4);
    uint2 h4 = *(const uint2*)(hb + (size_t)(p4 & 0xFFFFu) * 64 + sub * 4);
    uint2 h5 = *(const uint2*)(hb + (size_t)(p5 & 0xFFFFu) * 64 + sub * 4);
    uint2 h6 = *(const uint2*)(hb + (size_t)(p6 & 0xFFFFu) * 64 + sub * 4);
    uint2 h7 = *(const uint2*)(hb + (size_t)(p7 & 0xFFFFu) * 64 + sub * 4);
    float v0 = bfhi(p0), v1 = bfhi(p1), v2 = bfhi(p2), v3 = bfhi(p3);
    float v4 = bfhi(p4), v5 = bfhi(p5), v6 = bfhi(p6), v7 = bfhi(p7);
    a0 += v0*bflo(h0.x) + v1*bflo(h1.x) + v2*bflo(h2.x) + v3*bflo(h3.x)
        + v4*bflo(h4.x) + v5*bflo(h5.x) + v6*bflo(h6.x) + v7*bflo(h7.x);
    a1 += v0*bfhi(h0.x) + v1*bfhi(h1.x) + v2*bfhi(h2.x) + v3*bfhi(h3.x)
        + v4*bfhi(h4.x) + v5*bfhi(h5.x) + v6*bfhi(h6.x) + v7*bfhi(h7.x);
    a2 += v0*bflo(h0.y) + v1*bflo(h1.y) + v2*bflo(h2.y) + v3*bflo(h3.y)
        + v4*bflo(h4.y) + v5*bflo(h5.y) + v6*bflo(h6.y) + v7*bflo(h7.y);
    a3 += v0*bfhi(h0.y) + v1*bfhi(h1.y) + v2*bfhi(h2.y) + v3*bfhi(h3.y)
        + v4*bfhi(h4.y) + v5*bfhi(h5.y) + v6*bfhi(h6.y) + v7*bfhi(h7.y);
  }
  for (; i < e; ++i) {
    unsigned pe = csr[i];
    float v = bfhi(pe);
    uint2 hv = *(const uint2*)(hb + (size_t)(pe & 0xFFFFu) * 64 + sub * 4);
    a0 += v * bflo(hv.x); a1 += v * bfhi(hv.x);
    a2 += v * bflo(hv.y); a3 += v * bfhi(hv.y);
  }
  float d = dis[n];
  uint2 pk;
  pk.x = (unsigned)f2bf(d * a0) | ((unsigned)f2bf(d * a1) << 16);
  pk.y = (unsigned)f2bf(d * a2) | ((unsigned)f2bf(d * a3) << 16);
  *(uint2*)(aggb + (size_t)n * 64 + sub * 4) = pk;
}

// ---- MFMA dense 64->64 + bias + sigmoid + *dis -> bf16 h' ------------------

__global__ __launch_bounds__(256) void k_dense64_mfma(
    const unsigned short* __restrict__ aggb, const unsigned short* __restrict__ Wb,
    const float* __restrict__ b, const float* __restrict__ dis,
    unsigned short* __restrict__ hb, int NS) {
  int wid = threadIdx.x >> 6, lane = threadIdx.x & 63;
  int quad = lane >> 4, r16 = lane & 15;
  bf16x8 Bf[2][4];
#pragma unroll
  for (int kt = 0; kt < 2; ++kt)
#pragma unroll
    for (int jt = 0; jt < 4; ++jt)
#pragma unroll
      for (int j = 0; j < 8; ++j)
        Bf[kt][jt][j] = (short)Wb[(kt * 32 + quad * 8 + j) * 64 + jt * 16 + r16];
  float bias[4];
#pragma unroll
  for (int jt = 0; jt < 4; ++jt) bias[jt] = b[jt * 16 + r16];
  int stride = gridDim.x * 4;
  for (int s = blockIdx.x * 4 + wid; s < NS; s += stride) {
    int n0 = s * 16;
    bf16x8 Af0 = *(const bf16x8*)(aggb + (size_t)(n0 + r16) * 64 + quad * 8);
    bf16x8 Af1 = *(const bf16x8*)(aggb + (size_t)(n0 + r16) * 64 + 32 + quad * 8);
    f32x4 C[4];
#pragma unroll
    for (int jt = 0; jt < 4; ++jt) {
      f32x4 z = {0.f, 0.f, 0.f, 0.f};
      z = __builtin_amdgcn_mfma_f32_16x16x32_bf16(Af0, Bf[0][jt], z, 0, 0, 0);
      z = __builtin_amdgcn_mfma_f32_16x16x32_bf16(Af1, Bf[1][jt], z, 0, 0, 0);
      C[jt] = z;
    }
    float dv[4];
#pragma unroll
    for (int reg = 0; reg < 4; ++reg) dv[reg] = dis[n0 + quad * 4 + reg];
#pragma unroll
    for (int jt = 0; jt < 4; ++jt)
#pragma unroll
      for (int reg = 0; reg < 4; ++reg) {
        float h = dv[reg] / (1.0f + expf(-(C[jt][reg] + bias[jt])));
        hb[(size_t)(n0 + quad * 4 + reg) * 64 + jt * 16 + r16] = f2bf(h);
      }
  }
}

// ---- MFMA layer-3 dense + sigmoid + logit + exp + partial sum --------------

__global__ __launch_bounds__(256) void k_head_mfma(
    const unsigned short* __restrict__ aggb, const unsigned short* __restrict__ Wb,
    const float* __restrict__ b, const float* __restrict__ Wl,
    const float* __restrict__ bl, float* __restrict__ expv,
    float* __restrict__ red_part, int NS) {
  int wid = threadIdx.x >> 6, lane = threadIdx.x & 63;
  int quad = lane >> 4, r16 = lane & 15;
  bf16x8 Bf[2][4];
#pragma unroll
  for (int kt = 0; kt < 2; ++kt)
#pragma unroll
    for (int jt = 0; jt < 4; ++jt)
#pragma unroll
      for (int j = 0; j < 8; ++j)
        Bf[kt][jt][j] = (short)Wb[(kt * 32 + quad * 8 + j) * 64 + jt * 16 + r16];
  float bias[4], wlv[4];
#pragma unroll
  for (int jt = 0; jt < 4; ++jt) {
    bias[jt] = b[jt * 16 + r16];
    wlv[jt]  = Wl[jt * 16 + r16];
  }
  float bl0 = bl[0];
  float lsum = 0.0f;
  int stride = gridDim.x * 4;
  for (int s = blockIdx.x * 4 + wid; s < NS; s += stride) {
    int n0 = s * 16;
    bf16x8 Af0 = *(const bf16x8*)(aggb + (size_t)(n0 + r16) * 64 + quad * 8);
    bf16x8 Af1 = *(const bf16x8*)(aggb + (size_t)(n0 + r16) * 64 + 32 + quad * 8);
    f32x4 C[4];
#pragma unroll
    for (int jt = 0; jt < 4; ++jt) {
      f32x4 z = {0.f, 0.f, 0.f, 0.f};
      z = __builtin_amdgcn_mfma_f32_16x16x32_bf16(Af0, Bf[0][jt], z, 0, 0, 0);
      z = __builtin_amdgcn_mfma_f32_16x16x32_bf16(Af1, Bf[1][jt], z, 0, 0, 0);
      C[jt] = z;
    }
    float p0 = 0, p1 = 0, p2 = 0, p3 = 0;
#pragma unroll
    for (int jt = 0; jt < 4; ++jt) {
      p0 += wlv[jt] / (1.0f + expf(-(C[jt][0] + bias[jt])));
      p1 += wlv[jt] / (1.0f + expf(-(C[jt][1] + bias[jt])));
      p2 += wlv[jt] / (1.0f + expf(-(C[jt][2] + bias[jt])));
      p3 += wlv[jt] / (1.0f + expf(-(C[jt][3] + bias[jt])));
    }
#pragma unroll
    for (int m = 1; m < 16; m <<= 1) {        // reduce over the 16 cols/quad
      p0 += __shfl_xor(p0, m, 64);
      p1 += __shfl_xor(p1, m, 64);
      p2 += __shfl_xor(p2, m, 64);
      p3 += __shfl_xor(p3, m, 64);
    }
    float ls = 0.0f;
    if (r16 == 0) {
      float e0 = expf(p0 + bl0), e1 = expf(p1 + bl0);
      float e2 = expf(p2 + bl0), e3 = expf(p3 + bl0);
      int r = n0 + quad * 4;
      expv[r] = e0; expv[r + 1] = e1; expv[r + 2] = e2; expv[r + 3] = e3;
      ls = e0 + e1 + e2 + e3;
    }
    ls += __shfl_xor(ls, 16, 64);
    ls += __shfl_xor(ls, 32, 64);
    lsum += ls;                                // lane 0 holds wave total
  }
  if (lane == 0) atomicAdd(&red_part[(blockIdx.x & 63) << 4], lsum);
}

// scale by 1/sum (each wave reduces the 64 padded partials; L2-hot)
__global__ void k_out(const float* __restrict__ expv, int N,
                      const float* __restrict__ red_part, float* __restrict__ out) {
  int i = blockIdx.x * blockDim.x + threadIdx.x;
  int lane = threadIdx.x & 63;
  float s = red_part[lane << 4];
#pragma unroll
  for (int o = 32; o > 0; o >>= 1) s += __shfl_down(s, o, 64);
  s = __shfl(s, 0, 64);
  if (i < N) out[i] = expv[i] / s;
}

// ---------------------------------------------------------------------------

extern "C" void kernel_launch(void* const* d_in, const int* in_sizes, int n_in,
                              void* d_out, int out_size, void* d_ws, size_t ws_size,
                              hipStream_t stream) {
  const float* x   = (const float*)d_in[0];   // [N,6]
  const int*   edg = (const int*)d_in[1];     // [2,E] int32
  const float* w   = (const float*)d_in[2];   // [E]
  const float* W1  = (const float*)d_in[3];   // [6,64]
  const float* b1  = (const float*)d_in[4];
  const float* W2  = (const float*)d_in[5];   // [64,64]
  const float* b2  = (const float*)d_in[6];
  const float* W3  = (const float*)d_in[7];
  const float* b3  = (const float*)d_in[8];
  const float* Wl  = (const float*)d_in[9];   // [64,1]
  const float* bl  = (const float*)d_in[10];
  float* out = (float*)d_out;

  const int N = in_sizes[0] / 6;
  const int E = in_sizes[2];
  const int* row = edg;
  const int* col = edg + E;
  const int NB = (N + 255) >> 8;              // active buckets (196)
  const int NS = (N + 15) / 16;               // MFMA strips (3125)

  // ---- workspace layout ----
  size_t off = 0;
  char* base = (char*)d_ws;
  auto alloc = [&](size_t bytes) -> void* {
    void* p = base + off;
    off += (bytes + 255) & ~(size_t)255;
    return p;
  };
  int*   bfill    = (int*)alloc((size_t)SKB * 16 * 4);   // padded counters (zeroed)
  float* red_part = (float*)alloc((size_t)64 * 16 * 4);  // padded partials (zeroed)
  size_t zero_bytes = off;
  int*   cnt    = (int*)alloc((size_t)N * 4);
  int*   start  = (int*)alloc((size_t)N * 4);
  float* dis    = (float*)alloc((size_t)N * 4);
  float* expv   = (float*)alloc((size_t)N * 4);
  unsigned short* x8b = (unsigned short*)alloc((size_t)N * 8 * 2);   // bf16 x'
  unsigned short* hb  = (unsigned short*)alloc((size_t)N * 64 * 2);  // bf16 h'
  unsigned short* W2b = (unsigned short*)alloc(4096 * 2);
  unsigned short* W3b = (unsigned short*)alloc(4096 * 2);
  size_t remain = (ws_size > off) ? (ws_size - off) : 0;
  long long capn = ((long long)remain) / ((long long)NB * 12);
  int CAP = (int)capn;
  if (CAP > 9216) CAP = 9216;
  if (CAP < 8704) CAP = 8704;                 // mean 8163 + ~6 sigma floor
  unsigned* csr = (unsigned*)alloc((size_t)NB * CAP * 4);
  size_t aggsz = (size_t)N * 64 * 2;
  size_t bksz  = (size_t)NB * CAP * 8;
  void* shared_blk = alloc(aggsz > bksz ? aggsz : bksz);
  int2*           bucket = (int2*)shared_blk;           // dead after k_build
  unsigned short* aggb   = (unsigned short*)shared_blk; // bf16 agg buffer

  const int gE   = (E + CHUNK - 1) / CHUNK;   // 391 blocks
  const int gN   = (N + BLK - 1) / BLK;
  const int gN8  = (N * 8 + BLK - 1) / BLK;   // 8 threads per node (layer1)
  const int gN16 = (N * 16 + BLK - 1) / BLK;  // 16 threads per node (agg64)
  const int gM   = 200;                       // MFMA dense grid (800 waves)

  hipMemsetAsync(d_ws, 0, zero_bytes, stream);

  // CSR build + weight prep
  k_wprep     <<<16, BLK, 0, stream>>>(W2, W3, W2b, W3b);
  k_binscatter<<<gE, BLK, 0, stream>>>(row, col, w, E, bfill, bucket, CAP);
  k_build     <<<NB, BLK, 0, stream>>>(bucket, bfill, x, csr, cnt, start, dis, x8b, CAP, N);

  // layer 1 (fused agg + dense + sigmoid) -> hb (bf16)
  k_layer1<<<gN8, BLK, 0, stream>>>(x8b, start, cnt, csr, dis, W1, b1, hb, N);

  // layer 2: agg (bf16 gather -> bf16 agg) ; MFMA dense -> hb (bf16)
  k_agg64       <<<gN16, BLK, 0, stream>>>(hb, start, cnt, csr, dis, aggb, N);
  k_dense64_mfma<<<gM,   BLK, 0, stream>>>(aggb, W2b, b2, dis, hb, NS);

  // layer 3: agg ; MFMA dense fused with logits head + exp + partial sums
  k_agg64    <<<gN16, BLK, 0, stream>>>(hb, start, cnt, csr, dis, aggb, N);
  k_head_mfma<<<gM,   BLK, 0, stream>>>(aggb, W3b, b3, Wl, bl, expv, red_part, NS);

  // normalize
  k_out<<<gN, BLK, 0, stream>>>(expv, N, red_part, out);
}

// Round 12
// 215.491 us; speedup vs baseline: 1.1084x; 1.0892x over previous
//
#include <hip/hip_runtime.h>
#include <math.h>

// ---------------------------------------------------------------------------
// 3-layer GCN + softmax on MI355X.
// A(XW) = (AX)W -> aggregate first (F=6 for layer 1).
// R11: fused agg+MFMA at 16 nodes/block (3125 blocks -> same gather
//      concurrency as standalone agg64, unlike R7's 782-block attempt).
//      Kills both aggb round-trips + 2 dense launches; wprep folded into
//      binscatter tail. 7 launches + tiny memset.
// ---------------------------------------------------------------------------

#define BLK 256
#define SKB 256            // scatter buckets: b = col >> 8 (196 active)
#define CHUNK 4096         // edges staged per block in k_binscatter
#define LROW 72            // LDS tile row stride in shorts (144 B, 2-way max)

typedef __attribute__((ext_vector_type(8))) short bf16x8;
typedef __attribute__((ext_vector_type(4))) float f32x4;

__device__ inline unsigned short f2bf(float f) {      // fp32 -> bf16 (RNE)
  unsigned u = __float_as_uint(f);
  return (unsigned short)((u + 0x7FFF + ((u >> 16) & 1)) >> 16);
}
__device__ inline float bflo(unsigned u) { return __uint_as_float(u << 16); }
__device__ inline float bfhi(unsigned u) { return __uint_as_float(u & 0xFFFF0000u); }

// ---- pass A: LDS-binned scatter into fixed-capacity bucket regions ---------
// Entry: .x = row | (col << 16)  (N < 65536), .y = float bits of w.
// Tail blocks (>= nEB) convert W2/W3 to bf16.

__global__ __launch_bounds__(256) void k_binscatter(
    const int* __restrict__ row, const int* __restrict__ col,
    const float* __restrict__ w, int E,
    int* __restrict__ bfill, int2* __restrict__ bucket, int CAP, int nEB,
    const float* __restrict__ W2, const float* __restrict__ W3,
    unsigned short* __restrict__ W2b, unsigned short* __restrict__ W3b) {
  if (blockIdx.x >= nEB) {                     // wprep tail
    int i = (blockIdx.x - nEB) * BLK + threadIdx.x;
    if (i < 4096) { W2b[i] = f2bf(W2[i]); W3b[i] = f2bf(W3[i]); }
    return;
  }
  __shared__ int2 stage[CHUNK];
  __shared__ int lhist[SKB], lbase[SKB], gbase[SKB], lfill[SKB];
  int t = threadIdx.x;
  int e0 = blockIdx.x * CHUNK;
  int n = E - e0; if (n > CHUNK) n = CHUNK;
  lhist[t] = 0; lfill[t] = 0;
  __syncthreads();
  for (int i = t; i < n; i += BLK) atomicAdd(&lhist[((unsigned)col[e0 + i]) >> 8], 1);
  __syncthreads();
  lbase[t] = lhist[t];
  __syncthreads();
  for (int off = 1; off < SKB; off <<= 1) {
    int v = (t >= off) ? lbase[t - off] : 0;
    __syncthreads();
    lbase[t] += v;
    __syncthreads();
  }
  int excl = lbase[t] - lhist[t];
  int cb = lhist[t];
  gbase[t] = cb ? atomicAdd(&bfill[t << 4], cb) : 0;   // reserve run space
  __syncthreads();
  lbase[t] = excl;
  __syncthreads();
  for (int i = t; i < n; i += BLK) {
    int c = col[e0 + i];
    int b = ((unsigned)c) >> 8;
    int r = atomicAdd(&lfill[b], 1);
    stage[lbase[b] + r] = make_int2(row[e0 + i] | (c << 16), __float_as_int(w[e0 + i]));
  }
  __syncthreads();
  for (int i = t; i < n; i += BLK) {
    int2 p = stage[i];
    int b = ((unsigned)p.x) >> 24;
    bucket[(size_t)b * CAP + gbase[b] + (i - lbase[b])] = p;
  }
}

// ---- pass B: workgroup per bucket -> node-ordered packed CSR + norms -------

__global__ __launch_bounds__(256) void k_build(
    const int2* __restrict__ bucket, const int* __restrict__ bfill,
    const float* __restrict__ x,
    unsigned* __restrict__ csr, int* __restrict__ cnt, int* __restrict__ start,
    float* __restrict__ dis, unsigned short* __restrict__ x8b, int CAP, int N) {
  __shared__ int   hist[SKB];
  __shared__ float wsum[SKB];
  __shared__ int   lstart[SKB + 1];
  __shared__ int   lfill[SKB];
  int b = blockIdx.x, t = threadIdx.x;
  int n0 = b << 8;
  int M = N - n0; if (M > 256) M = 256;
  if (M <= 0) return;
  hist[t] = 0; wsum[t] = 0.0f; lfill[t] = 0;
  __syncthreads();
  const int2* bb = bucket + (size_t)b * CAP;
  int ec = bfill[b << 4];
  for (int i = t; i < ec; i += BLK) {
    int2 p = bb[i];
    int lc = (((unsigned)p.x) >> 16) & 255;
    atomicAdd(&hist[lc], 1);
    atomicAdd(&wsum[lc], __int_as_float(p.y));          // exact fp32 degree
  }
  __syncthreads();
  if (t == 0) {
    int run = 0;
    for (int i = 0; i < M; ++i) { lstart[i] = run; run += hist[i]; }
    lstart[M] = run;
  }
  __syncthreads();
  if (t < M) {
    int n = n0 + t;
    cnt[n] = hist[t];
    start[n] = b * CAP + lstart[t];
    float d = 1.0f / sqrtf(wsum[t] + 1.0f);
    dis[n] = d;
    const float* xr = x + (size_t)n * 6;
    uint4 pk;
    pk.x = (unsigned)f2bf(d * xr[0]) | ((unsigned)f2bf(d * xr[1]) << 16);
    pk.y = (unsigned)f2bf(d * xr[2]) | ((unsigned)f2bf(d * xr[3]) << 16);
    pk.z = (unsigned)f2bf(d * xr[4]) | ((unsigned)f2bf(d * xr[5]) << 16);
    pk.w = 0u;
    *(uint4*)(x8b + (size_t)n * 8) = pk;
  }
  __syncthreads();
  for (int i = t; i < ec; i += BLK) {
    int2 p = bb[i];
    int lc = (((unsigned)p.x) >> 16) & 255;
    int pos = lstart[lc] + atomicAdd(&lfill[lc], 1);
    csr[(size_t)b * CAP + pos] =
        ((unsigned)p.x & 0xFFFFu) | ((unsigned)f2bf(__int_as_float(p.y)) << 16);
  }
}

// ---- layer 1: 8 lanes/node (R10). Lanes stripe edges, shfl reduce, dense ---

__global__ void k_layer1(const unsigned short* __restrict__ x8b,
                         const int* __restrict__ start, const int* __restrict__ cnt,
                         const unsigned* __restrict__ csr, const float* __restrict__ dis,
                         const float* __restrict__ W1, const float* __restrict__ b1,
                         unsigned short* __restrict__ hb, int N) {
  int t = blockIdx.x * blockDim.x + threadIdx.x;
  int n = t >> 3, sub = t & 7;
  if (n >= N) return;
  float a0 = 0.f, a1 = 0.f, a2 = 0.f, a3 = 0.f, a4 = 0.f, a5 = 0.f;
  if (sub == 0) {                              // self term = x'[n] on lane 0
    uint4 sv = *(const uint4*)(x8b + (size_t)n * 8);
    a0 = bflo(sv.x); a1 = bfhi(sv.x); a2 = bflo(sv.y);
    a3 = bfhi(sv.y); a4 = bflo(sv.z); a5 = bfhi(sv.z);
  }
  int s = start[n], e = s + cnt[n];
  int i = s + sub;
  for (; i + 8 < e; i += 16) {                 // 2 rows in flight per lane
    unsigned p0 = csr[i], p1 = csr[i + 8];
    uint4 h0 = *(const uint4*)(x8b + (size_t)(p0 & 0xFFFFu) * 8);
    uint4 h1 = *(const uint4*)(x8b + (size_t)(p1 & 0xFFFFu) * 8);
    float v0 = bfhi(p0), v1 = bfhi(p1);
    a0 += v0 * bflo(h0.x) + v1 * bflo(h1.x);
    a1 += v0 * bfhi(h0.x) + v1 * bfhi(h1.x);
    a2 += v0 * bflo(h0.y) + v1 * bflo(h1.y);
    a3 += v0 * bfhi(h0.y) + v1 * bfhi(h1.y);
    a4 += v0 * bflo(h0.z) + v1 * bflo(h1.z);
    a5 += v0 * bfhi(h0.z) + v1 * bfhi(h1.z);
  }
  for (; i < e; i += 8) {
    unsigned pe = csr[i];
    float v = bfhi(pe);
    uint4 hv = *(const uint4*)(x8b + (size_t)(pe & 0xFFFFu) * 8);
    a0 += v * bflo(hv.x); a1 += v * bfhi(hv.x);
    a2 += v * bflo(hv.y); a3 += v * bfhi(hv.y);
    a4 += v * bflo(hv.z); a5 += v * bfhi(hv.z);
  }
#pragma unroll
  for (int m = 1; m < 8; m <<= 1) {            // all 8 lanes end with full sums
    a0 += __shfl_xor(a0, m, 64); a1 += __shfl_xor(a1, m, 64);
    a2 += __shfl_xor(a2, m, 64); a3 += __shfl_xor(a3, m, 64);
    a4 += __shfl_xor(a4, m, 64); a5 += __shfl_xor(a5, m, 64);
  }
  float d = dis[n];
  a0 *= d; a1 *= d; a2 *= d; a3 *= d; a4 *= d; a5 *= d;
  unsigned short* o = hb + (size_t)n * 64;
#pragma unroll
  for (int jj = 0; jj < 2; ++jj) {             // each lane: 8 of 64 outputs
    int j4 = sub * 2 + jj;
    float4 acc = *(const float4*)(b1 + j4 * 4);
    const float* Wc = W1 + j4 * 4;
    acc.x += a0*Wc[0] + a1*Wc[64] + a2*Wc[128] + a3*Wc[192] + a4*Wc[256] + a5*Wc[320];
    acc.y += a0*Wc[1] + a1*Wc[65] + a2*Wc[129] + a3*Wc[193] + a4*Wc[257] + a5*Wc[321];
    acc.z += a0*Wc[2] + a1*Wc[66] + a2*Wc[130] + a3*Wc[194] + a4*Wc[258] + a5*Wc[322];
    acc.w += a0*Wc[3] + a1*Wc[67] + a2*Wc[131] + a3*Wc[195] + a4*Wc[259] + a5*Wc[323];
    uint2 pk;
    pk.x = (unsigned)f2bf(d / (1.0f + expf(-acc.x))) |
           ((unsigned)f2bf(d / (1.0f + expf(-acc.y))) << 16);
    pk.y = (unsigned)f2bf(d / (1.0f + expf(-acc.z))) |
           ((unsigned)f2bf(d / (1.0f + expf(-acc.w))) << 16);
    *(uint2*)(o + j4 * 4) = pk;
  }
}

// ---- agg phase helper: 16 lanes/node, 8-deep, result bf16 -> LDS tile ------

__device__ inline void agg16(const unsigned short* __restrict__ hb,
                             const int* __restrict__ start,
                             const int* __restrict__ cnt,
                             const unsigned* __restrict__ csr,
                             const float* __restrict__ dis,
                             unsigned short* lag, int n0, int N) {
  int t = threadIdx.x;
  int r = t >> 4, sub = t & 15;
  int n = n0 + r;
  uint2 pk = make_uint2(0u, 0u);
  if (n < N) {
    uint2 sv = *(const uint2*)(hb + (size_t)n * 64 + sub * 4);  // self
    float a0 = bflo(sv.x), a1 = bfhi(sv.x), a2 = bflo(sv.y), a3 = bfhi(sv.y);
    int s = start[n], e = s + cnt[n];
    int i = s;
    for (; i + 8 <= e; i += 8) {               // 8 independent chains
      unsigned p0 = csr[i],     p1 = csr[i + 1], p2 = csr[i + 2], p3 = csr[i + 3];
      unsigned p4 = csr[i + 4], p5 = csr[i + 5], p6 = csr[i + 6], p7 = csr[i + 7];
      uint2 h0 = *(const uint2*)(hb + (size_t)(p0 & 0xFFFFu) * 64 + sub * 4);
      uint2 h1 = *(const uint2*)(hb + (size_t)(p1 & 0xFFFFu) * 64 + sub * 4);
      uint2 h2 = *(const uint2*)(hb + (size_t)(p2 & 0xFFFFu) * 64 + sub * 4);
      uint2 h3 = *(const uint2*)(hb + (size_t)(p3 & 0xFFFFu) * 64 + sub * 4);
      uint2 h4 = *(const uint2*)(hb + (size_t)(p4 & 0xFFFFu) * 64 + sub * 4);
      uint2 h5 = *(const uint2*)(hb + (size_t)(p5 & 0xFFFFu) * 64 + sub * 4);
      uint2 h6 = *(const uint2*)(hb + (size_t)(p6 & 0xFFFFu) * 64 + sub * 4);
      uint2 h7 = *(const uint2*)(hb + (size_t)(p7 & 0xFFFFu) * 64 + sub * 4);
      float v0 = bfhi(p0), v1 = bfhi(p1), v2 = bfhi(p2), v3 = bfhi(p3);
      float v4 = bfhi(p4), v5 = bfhi(p5), v6 = bfhi(p6), v7 = bfhi(p7);
      a0 += v0*bflo(h0.x) + v1*bflo(h1.x) + v2*bflo(h2.x) + v3*bflo(h3.x)
          + v4*bflo(h4.x) + v5*bflo(h5.x) + v6*bflo(h6.x) + v7*bflo(h7.x);
      a1 += v0*bfhi(h0.x) + v1*bfhi(h1.x) + v2*bfhi(h2.x) + v3*bfhi(h3.x)
          + v4*bfhi(h4.x) + v5*bfhi(h5.x) + v6*bfhi(h6.x) + v7*bfhi(h7.x);
      a2 += v0*bflo(h0.y) + v1*bflo(h1.y) + v2*bflo(h2.y) + v3*bflo(h3.y)
          + v4*bflo(h4.y) + v5*bflo(h5.y) + v6*bflo(h6.y) + v7*bflo(h7.y);
      a3 += v0*bfhi(h0.y) + v1*bfhi(h1.y) + v2*bfhi(h2.y) + v3*bfhi(h3.y)
          + v4*bfhi(h4.y) + v5*bfhi(h5.y) + v6*bfhi(h6.y) + v7*bfhi(h7.y);
    }
    for (; i < e; ++i) {
      unsigned pe = csr[i];
      float v = bfhi(pe);
      uint2 hv = *(const uint2*)(hb + (size_t)(pe & 0xFFFFu) * 64 + sub * 4);
      a0 += v * bflo(hv.x); a1 += v * bfhi(hv.x);
      a2 += v * bflo(hv.y); a3 += v * bfhi(hv.y);
    }
    float d = dis[n];
    pk.x = (unsigned)f2bf(d * a0) | ((unsigned)f2bf(d * a1) << 16);
    pk.y = (unsigned)f2bf(d * a2) | ((unsigned)f2bf(d * a3) << 16);
  }
  *(uint2*)(lag + r * LROW + sub * 4) = pk;
}

// ---- layer 2 fused: agg (16 nodes/block) -> LDS -> MFMA -> sigmoid -> h2' --
// MFMA: A = 16x64 tile; wave wid handles output cols [wid*16, wid*16+16).

__global__ __launch_bounds__(256) void k_layer2f(
    const unsigned short* __restrict__ hb_in,
    const int* __restrict__ start, const int* __restrict__ cnt,
    const unsigned* __restrict__ csr, const float* __restrict__ dis,
    const unsigned short* __restrict__ Wb, const float* __restrict__ b,
    unsigned short* __restrict__ hb_out, int N) {
  __shared__ unsigned short lag[16 * LROW];
  int n0 = blockIdx.x * 16;
  agg16(hb_in, start, cnt, csr, dis, lag, n0, N);
  __syncthreads();
  int t = threadIdx.x;
  int wid = t >> 6, lane = t & 63, quad = lane >> 4, r16 = lane & 15;
  bf16x8 Af0 = *(const bf16x8*)(lag + r16 * LROW + quad * 8);
  bf16x8 Af1 = *(const bf16x8*)(lag + r16 * LROW + 32 + quad * 8);
  bf16x8 Bf0, Bf1;
#pragma unroll
  for (int j = 0; j < 8; ++j) {
    Bf0[j] = (short)Wb[(quad * 8 + j) * 64 + wid * 16 + r16];
    Bf1[j] = (short)Wb[(32 + quad * 8 + j) * 64 + wid * 16 + r16];
  }
  f32x4 z = {0.f, 0.f, 0.f, 0.f};
  z = __builtin_amdgcn_mfma_f32_16x16x32_bf16(Af0, Bf0, z, 0, 0, 0);
  z = __builtin_amdgcn_mfma_f32_16x16x32_bf16(Af1, Bf1, z, 0, 0, 0);
  float bias = b[wid * 16 + r16];
#pragma unroll
  for (int reg = 0; reg < 4; ++reg) {          // C/D: col=lane&15-block, row=quad*4+reg
    int nb = n0 + quad * 4 + reg;
    if (nb < N) {
      float h = dis[nb] / (1.0f + expf(-(z[reg] + bias)));
      hb_out[(size_t)nb * 64 + wid * 16 + r16] = f2bf(h);
    }
  }
}

// ---- layer 3 fused: agg -> LDS -> MFMA -> sigmoid -> logit -> exp -> sum ---

__global__ __launch_bounds__(256) void k_layer3f(
    const unsigned short* __restrict__ hb_in,
    const int* __restrict__ start, const int* __restrict__ cnt,
    const unsigned* __restrict__ csr, const float* __restrict__ dis,
    const unsigned short* __restrict__ Wb, const float* __restrict__ b,
    const float* __restrict__ Wl, const float* __restrict__ bl,
    float* __restrict__ expv, float* __restrict__ red_part, int N) {
  __shared__ unsigned short lag[16 * LROW];
  __shared__ float psum[16][4];
  int n0 = blockIdx.x * 16;
  agg16(hb_in, start, cnt, csr, dis, lag, n0, N);
  __syncthreads();
  int t = threadIdx.x;
  int wid = t >> 6, lane = t & 63, quad = lane >> 4, r16 = lane & 15;
  bf16x8 Af0 = *(const bf16x8*)(lag + r16 * LROW + quad * 8);
  bf16x8 Af1 = *(const bf16x8*)(lag + r16 * LROW + 32 + quad * 8);
  bf16x8 Bf0, Bf1;
#pragma unroll
  for (int j = 0; j < 8; ++j) {
    Bf0[j] = (short)Wb[(quad * 8 + j) * 64 + wid * 16 + r16];
    Bf1[j] = (short)Wb[(32 + quad * 8 + j) * 64 + wid * 16 + r16];
  }
  f32x4 z = {0.f, 0.f, 0.f, 0.f};
  z = __builtin_amdgcn_mfma_f32_16x16x32_bf16(Af0, Bf0, z, 0, 0, 0);
  z = __builtin_amdgcn_mfma_f32_16x16x32_bf16(Af1, Bf1, z, 0, 0, 0);
  float bias = b[wid * 16 + r16];
  float wl = Wl[wid * 16 + r16];
  float p[4];
#pragma unroll
  for (int reg = 0; reg < 4; ++reg)
    p[reg] = wl / (1.0f + expf(-(z[reg] + bias)));
#pragma unroll
  for (int m = 1; m < 16; m <<= 1) {           // reduce over this wave's 16 cols
#pragma unroll
    for (int reg = 0; reg < 4; ++reg) p[reg] += __shfl_xor(p[reg], m, 64);
  }
  if (r16 == 0) {
#pragma unroll
    for (int reg = 0; reg < 4; ++reg) psum[quad * 4 + reg][wid] = p[reg];
  }
  __syncthreads();
  if (t < 16) {                                // lanes 0-15 of wave 0
    int n = n0 + t;
    float lg = psum[t][0] + psum[t][1] + psum[t][2] + psum[t][3] + bl[0];
    float ev = (n < N) ? expf(lg) : 0.f;       // logits bounded; no max shift
    if (n < N) expv[n] = ev;
#pragma unroll
    for (int m = 1; m < 16; m <<= 1) ev += __shfl_xor(ev, m, 64);
    if (t == 0) atomicAdd(&red_part[(blockIdx.x & 63) << 4], ev);
  }
}

// scale by 1/sum (each wave reduces the 64 padded partials; L2-hot)
__global__ void k_out(const float* __restrict__ expv, int N,
                      const float* __restrict__ red_part, float* __restrict__ out) {
  int i = blockIdx.x * blockDim.x + threadIdx.x;
  int lane = threadIdx.x & 63;
  float s = red_part[lane << 4];
#pragma unroll
  for (int o = 32; o > 0; o >>= 1) s += __shfl_down(s, o, 64);
  s = __shfl(s, 0, 64);
  if (i < N) out[i] = expv[i] / s;
}

// ---------------------------------------------------------------------------

extern "C" void kernel_launch(void* const* d_in, const int* in_sizes, int n_in,
                              void* d_out, int out_size, void* d_ws, size_t ws_size,
                              hipStream_t stream) {
  const float* x   = (const float*)d_in[0];   // [N,6]
  const int*   edg = (const int*)d_in[1];     // [2,E] int32
  const float* w   = (const float*)d_in[2];   // [E]
  const float* W1  = (const float*)d_in[3];   // [6,64]
  const float* b1  = (const float*)d_in[4];
  const float* W2  = (const float*)d_in[5];   // [64,64]
  const float* b2  = (const float*)d_in[6];
  const float* W3  = (const float*)d_in[7];
  const float* b3  = (const float*)d_in[8];
  const float* Wl  = (const float*)d_in[9];   // [64,1]
  const float* bl  = (const float*)d_in[10];
  float* out = (float*)d_out;

  const int N = in_sizes[0] / 6;
  const int E = in_sizes[2];
  const int* row = edg;
  const int* col = edg + E;
  const int NB = (N + 255) >> 8;              // active buckets (196)

  // ---- workspace layout ----
  size_t off = 0;
  char* base = (char*)d_ws;
  auto alloc = [&](size_t bytes) -> void* {
    void* p = base + off;
    off += (bytes + 255) & ~(size_t)255;
    return p;
  };
  int*   bfill    = (int*)alloc((size_t)SKB * 16 * 4);   // padded counters (zeroed)
  float* red_part = (float*)alloc((size_t)64 * 16 * 4);  // padded partials (zeroed)
  size_t zero_bytes = off;
  int*   cnt    = (int*)alloc((size_t)N * 4);
  int*   start  = (int*)alloc((size_t)N * 4);
  float* dis    = (float*)alloc((size_t)N * 4);
  float* expv   = (float*)alloc((size_t)N * 4);
  unsigned short* x8b = (unsigned short*)alloc((size_t)N * 8 * 2);   // bf16 x'
  unsigned short* hb  = (unsigned short*)alloc((size_t)N * 64 * 2);  // bf16 h1'
  unsigned short* W2b = (unsigned short*)alloc(4096 * 2);
  unsigned short* W3b = (unsigned short*)alloc(4096 * 2);
  size_t remain = (ws_size > off) ? (ws_size - off) : 0;
  long long capn = ((long long)remain) / ((long long)NB * 12);
  int CAP = (int)capn;
  if (CAP > 9216) CAP = 9216;
  if (CAP < 8704) CAP = 8704;                 // mean 8163 + ~6 sigma floor
  unsigned* csr = (unsigned*)alloc((size_t)NB * CAP * 4);
  size_t h2sz = (size_t)N * 64 * 2;
  size_t bksz = (size_t)NB * CAP * 8;
  void* shared_blk = alloc(h2sz > bksz ? h2sz : bksz);
  int2*           bucket = (int2*)shared_blk;           // dead after k_build
  unsigned short* hb2    = (unsigned short*)shared_blk; // bf16 h2'

  const int nEB = (E + CHUNK - 1) / CHUNK;    // 391 scatter blocks
  const int gE  = nEB + 16;                   // + wprep tail
  const int gN  = (N + BLK - 1) / BLK;
  const int gN8 = (N * 8 + BLK - 1) / BLK;    // 8 threads per node (layer1)
  const int g16 = (N + 15) / 16;              // fused blocks: 16 nodes each

  hipMemsetAsync(d_ws, 0, zero_bytes, stream);

  // CSR build (+ weight prep in tail blocks)
  k_binscatter<<<gE, BLK, 0, stream>>>(row, col, w, E, bfill, bucket, CAP,
                                       nEB, W2, W3, W2b, W3b);
  k_build     <<<NB, BLK, 0, stream>>>(bucket, bfill, x, csr, cnt, start, dis, x8b, CAP, N);

  // layer 1 (fused agg + dense + sigmoid) -> hb (bf16)
  k_layer1<<<gN8, BLK, 0, stream>>>(x8b, start, cnt, csr, dis, W1, b1, hb, N);

  // layer 2 fused: agg -> LDS -> MFMA -> h2' (bucket region, dead after build)
  k_layer2f<<<g16, BLK, 0, stream>>>(hb, start, cnt, csr, dis, W2b, b2, hb2, N);

  // layer 3 fused: agg -> LDS -> MFMA -> head -> exp + partial sums
  k_layer3f<<<g16, BLK, 0, stream>>>(hb2, start, cnt, csr, dis, W3b, b3,
                                     Wl, bl, expv, red_part, N);

  // normalize
  k_out<<<gN, BLK, 0, stream>>>(expv, N, red_part, out);
}